// Round 6
// baseline (369.035 us; speedup 1.0000x reference)
//
#include <hip/hip_runtime.h>
#include <hip/hip_bf16.h>

// ---------- types ----------
typedef __attribute__((ext_vector_type(8))) short short8;   // 8 bf16 = 4 VGPR
typedef __attribute__((ext_vector_type(4))) float f32x4;    // MFMA C/D frag

__device__ __forceinline__ short f2bf(float f) {
  union { float f; unsigned u; } x; x.f = f;
  unsigned r = x.u + 0x7fffu + ((x.u >> 16) & 1u);   // RNE
  return (short)(r >> 16);
}

// async 16B/lane global->LDS. LDS dest = wave-uniform base + lane*16.
__device__ __forceinline__ void gload16(const short* g, short* l) {
  __builtin_amdgcn_global_load_lds(
      (const __attribute__((address_space(1))) unsigned*)g,
      (__attribute__((address_space(3))) unsigned*)l, 16, 0, 0);
}

// ---------- prep kernels ----------
__global__ void cast_bf16_kernel(const float* __restrict__ src,
                                 short* __restrict__ dst, int n) {
  int i = (blockIdx.x * 256 + threadIdx.x) * 4;
  if (i < n) {
    float4 f = *(const float4*)(src + i);
    union { short s[4]; uint2 u; } o;
    o.s[0] = f2bf(f.x); o.s[1] = f2bf(f.y);
    o.s[2] = f2bf(f.z); o.s[3] = f2bf(f.w);
    *(uint2*)(dst + i) = o.u;
  }
}

// src [R][C] fp32 -> dst [C][R] bf16, 64x64 LDS-tiled (coalesced both sides)
__global__ __launch_bounds__(256) void transpose_cast_kernel(
    const float* __restrict__ src, short* __restrict__ dst, int R, int C) {
  __shared__ short tile[64][72];
  int tpc = C >> 6;
  int bx = blockIdx.x % tpc, by = blockIdx.x / tpc;
  int r0 = by * 64, c0 = bx * 64;
  int tx = threadIdx.x & 15, ty = threadIdx.x >> 4;
#pragma unroll
  for (int i = 0; i < 4; i++) {
    int r = i * 16 + ty;
    float4 f = *(const float4*)(src + (size_t)(r0 + r) * C + c0 + tx * 4);
    union { short s[4]; uint2 u; } o;
    o.s[0] = f2bf(f.x); o.s[1] = f2bf(f.y);
    o.s[2] = f2bf(f.z); o.s[3] = f2bf(f.w);
    *(uint2*)&tile[r][tx * 4] = o.u;
  }
  __syncthreads();
#pragma unroll
  for (int i = 0; i < 4; i++) {
    int c = i * 16 + ty;
    union { short s[4]; uint2 u; } o;
#pragma unroll
    for (int k = 0; k < 4; k++) o.s[k] = tile[tx * 4 + k][c];
    *(uint2*)(dst + (size_t)(c0 + c) * R + r0 + tx * 4) = o.u;
  }
}

// V [b,h,n,dh] -> Vt [b,h,dh,n], 64x64 LDS-tiled per (bh, ntile)
__global__ __launch_bounds__(256) void vtrans_kernel(
    const short* __restrict__ Vb, short* __restrict__ Vt) {
  __shared__ short tile[64 * 73 + 8];   // stride 73: bank-rotating for gather
  int t = threadIdx.x;
  int bh = blockIdx.x & 31, ntile = blockIdx.x >> 5;
  const short* src = Vb + ((size_t)bh << 17) + (size_t)ntile * 64 * 64;
  short* dst = Vt + ((size_t)bh << 17) + ntile * 64;
#pragma unroll
  for (int i = 0; i < 2; i++) {
    int lin = t + 256 * i;
    int row = lin >> 3, u = lin & 7;
    union { short s[8]; uint4 v; } d;
    d.v = *(const uint4*)(src + row * 64 + u * 8);
#pragma unroll
    for (int j = 0; j < 8; j++) tile[row * 73 + u * 8 + j] = d.s[j];
  }
  __syncthreads();
#pragma unroll
  for (int i = 0; i < 2; i++) {
    int lin = t + 256 * i;
    int dh = lin >> 3, u = lin & 7;
    union { short s[8]; uint4 v; } d;
#pragma unroll
    for (int j = 0; j < 8; j++) d.s[j] = tile[(8 * u + j) * 73 + dh];
    *(uint4*)(dst + (size_t)dh * 2048 + 8 * u) = d.v;
  }
}

// ---------- GEMM core: C[128x128] = A[M,K] * Bt[N,K]^T ----------
__device__ __forceinline__ void gemm_core(
    const short* __restrict__ A, const short* __restrict__ Bt, int K,
    int mblk, int nblk, short* sA, short* sB, f32x4 (&acc)[4][4]) {
  int tid = threadIdx.x;
  int lane = tid & 63, wave = tid >> 6;
  int quad = lane >> 4, l15 = lane & 15;
  int wm = (wave >> 1) * 64, wn = (wave & 1) * 64;
  int sub = lane >> 3, e8 = lane & 7;
  int swz = (e8 ^ sub) << 3;              // global-side unit permutation
  int s0 = (quad ^ (l15 & 7)) << 3;       // frag slot offset (h=0)
  const short* Ag = A + (size_t)(mblk + 32 * wave + sub) * K + swz;
  const short* Bg = Bt + (size_t)(nblk + 32 * wave + sub) * K + swz;
  short* Al = sA + 4 * wave * 512;        // wave-uniform LDS bases
  short* Bl = sB + 4 * wave * 512;

  for (int k0 = 0; k0 < K; k0 += 64) {
    __syncthreads();
#pragma unroll
    for (int t = 0; t < 4; t++) {
      gload16(Ag + (size_t)(8 * t) * K + k0, Al + t * 512);
      gload16(Bg + (size_t)(8 * t) * K + k0, Bl + t * 512);
    }
    __syncthreads();
#pragma unroll
    for (int h = 0; h < 2; h++) {
      int so = s0 ^ (h << 5);
      short8 af[4], bf[4];
#pragma unroll
      for (int mt = 0; mt < 4; mt++)
        af[mt] = *(const short8*)(&sA[(wm + mt * 16 + l15) * 64 + so]);
#pragma unroll
      for (int nt = 0; nt < 4; nt++)
        bf[nt] = *(const short8*)(&sB[(wn + nt * 16 + l15) * 64 + so]);
#pragma unroll
      for (int mt = 0; mt < 4; mt++)
#pragma unroll
        for (int nt = 0; nt < 4; nt++)
          acc[mt][nt] = __builtin_amdgcn_mfma_f32_16x16x32_bf16(
              af[mt], bf[nt], acc[mt][nt], 0, 0, 0);
    }
  }
}

// Fused QKV projection -> all write [b,h,n,dh]. z=0 Q (scaled), z=1 K, z=2 V.
__global__ __launch_bounds__(256) void gemm_qkv(
    const short* __restrict__ xb, const short* __restrict__ cb,
    const short* __restrict__ wqt, const short* __restrict__ wkt,
    const short* __restrict__ wvt,
    const float* __restrict__ bq, const float* __restrict__ bk,
    const float* __restrict__ bv,
    short* __restrict__ Qb, short* __restrict__ Kb, short* __restrict__ Vb) {
  __shared__ __align__(16) short sA[128 * 64];
  __shared__ __align__(16) short sB[128 * 64];
  int z = blockIdx.z;
  const short* A  = (z == 0) ? xb : cb;
  const short* Bt = (z == 0) ? wqt : (z == 1) ? wkt : wvt;
  const float* bias = (z == 0) ? bq : (z == 1) ? bk : bv;
  short* out = (z == 0) ? Qb : (z == 1) ? Kb : Vb;
  float scale = (z == 0) ? 0.18033688011112042f : 1.0f;  // 0.125*log2(e)
  int mblk = blockIdx.x * 128, nblk = blockIdx.y * 128;
  f32x4 acc[4][4] = {};
  gemm_core(A, Bt, 1024, mblk, nblk, sA, sB, acc);

  int lane = threadIdx.x & 63, wave = threadIdx.x >> 6;
  int quad = lane >> 4, l15 = lane & 15;
  int wm = (wave >> 1) * 64, wn = (wave & 1) * 64;
#pragma unroll
  for (int nt = 0; nt < 4; nt++) {
    int col = nblk + wn + nt * 16 + l15;   // 0..511 = h*64+dh
    float bias_v = bias[col];
    int h = col >> 6, dh = col & 63;
#pragma unroll
    for (int mt = 0; mt < 4; mt++)
#pragma unroll
      for (int r = 0; r < 4; r++) {
        int row = mblk + wm + mt * 16 + quad * 4 + r;  // 0..8191 = b*2048+n
        float v = (acc[mt][nt][r] + bias_v) * scale;
        int b = row >> 11, n = row & 2047;
        size_t idx = (((size_t)(b * 8 + h)) << 17) + ((size_t)n << 6) + dh;
        out[idx] = f2bf(v);
      }
  }
}

// Output projection: out[8192,1024] fp32 = Ob[8192,512] @ wot[1024,512]^T + bo
__global__ __launch_bounds__(256) void gemm_out(
    const short* __restrict__ Ob, const short* __restrict__ wot,
    const float* __restrict__ bo, float* __restrict__ out) {
  __shared__ __align__(16) short sA[128 * 64];
  __shared__ __align__(16) short sB[128 * 64];
  int mblk = blockIdx.x * 128, nblk = blockIdx.y * 128;
  f32x4 acc[4][4] = {};
  gemm_core(Ob, wot, 512, mblk, nblk, sA, sB, acc);
  int lane = threadIdx.x & 63, wave = threadIdx.x >> 6;
  int quad = lane >> 4, l15 = lane & 15;
  int wm = (wave >> 1) * 64, wn = (wave & 1) * 64;
#pragma unroll
  for (int nt = 0; nt < 4; nt++) {
    int col = nblk + wn + nt * 16 + l15;
    float bias_v = bo[col];
#pragma unroll
    for (int mt = 0; mt < 4; mt++)
#pragma unroll
      for (int r = 0; r < 4; r++) {
        int row = mblk + wm + mt * 16 + quad * 4 + r;
        out[(size_t)row * 1024 + col] = acc[mt][nt][r] + bias_v;
      }
  }
}

// ---------- flash attention, k-strip decomposition ----------
// Block = 64 q x 2048 keys. Per 128-key tile: block stages K[128][64] +
// V^T[64][128] (XOR-swizzled, conflict-free); wave w owns keys 32w..32w+31
// and computes ALL 64 q against its strip (QK 16 MFMA + PV 16 MFMA).
// LDS frag traffic per wave-iter: 8KB vs R5's 16KB/64keys -> 4x less per key.
// One-time 4-way cross-wave O/lsum reduction at the end.
__global__ __launch_bounds__(256, 2) void attn_kernel(
    const short* __restrict__ Qb, const short* __restrict__ Kb,
    const short* __restrict__ Vt, short* __restrict__ Ob) {
  __shared__ __align__(16) short smem[26624];          // 52 KB
  short* sK = smem;                                    // [128 key][64 dh]
  short* sV = smem + 8192;                             // [64 dh][128 key]
  unsigned* sP = (unsigned*)(smem + 16384);            // 4 waves x 1280 dw
  int tid = threadIdx.x;
  int lane = tid & 63, wave = tid >> 6;
  int quad = lane >> 4, l15 = lane & 15;
  int bh = blockIdx.x & 31, qt = blockIdx.x >> 5;      // bh&7 -> XCD pinning
  const short* Qp = Qb + ((size_t)bh << 17);
  const short* Kp = Kb + ((size_t)bh << 17);
  const short* Vp = Vt + ((size_t)bh << 17);
  int qrow0 = qt * 64;
  // Q frags (B-operand) for all 64 q, live whole kernel (32 VGPR)
  short8 qf[4][2];
#pragma unroll
  for (int g = 0; g < 4; g++)
#pragma unroll
    for (int h = 0; h < 2; h++)
      qf[g][h] = *(const short8*)(Qp + (size_t)(qrow0 + 16 * g + l15) * 64 +
                                  32 * h + quad * 8);
  f32x4 o[4][4] = {};    // o[nt][g]: O^T[dh=16nt+4quad+r][q=16g+l15] partial
  float lsum[4] = {0.f, 0.f, 0.f, 0.f};

  // staging geometry (wave stages its own K strip + dh rows 16w..16w+15 of V)
  int sub = lane >> 3, e8 = lane & 7;        // K: row-in-8, 16B unit
  int sub4 = lane >> 4, u16 = lane & 15;     // V: row-in-4, 16B unit
  const short* kgb = Kp + (size_t)(32 * wave + sub) * 64 + e8 * 8;
  short* klb = sK + (32 * wave + sub) * 64 + ((e8 ^ sub) << 3);
  const short* vgb = Vp + (size_t)(16 * wave + sub4) * 2048 + u16 * 8;
  short* vlb = sV + (16 * wave + sub4) * 128;
  unsigned* pPw = sP + wave * 1280;

  // prefetch tile 0
  uint4 rk[4], rv[4];
#pragma unroll
  for (int t = 0; t < 4; t++) {
    rk[t] = *(const uint4*)(kgb + (size_t)(8 * t) * 64);
    rv[t] = *(const uint4*)(vgb + (size_t)(4 * t) * 2048);
  }

  for (int it = 0; it < 16; ++it) {
    __syncthreads();                         // prev tile readers done
#pragma unroll
    for (int t = 0; t < 4; t++) {
      *(uint4*)(klb + 8 * t * 64) = rk[t];
      *(uint4*)(vlb + 4 * t * 128 + ((u16 ^ ((4 * t + sub4) & 15)) << 3)) = rv[t];
    }
    if (it < 15) {
      int kb = (it + 1) * 128;
#pragma unroll
      for (int t = 0; t < 4; t++) {
        rk[t] = *(const uint4*)(kgb + (size_t)(kb + 8 * t) * 64);
        rv[t] = *(const uint4*)(vgb + (size_t)(4 * t) * 2048 + kb);
      }
    }
    __syncthreads();                         // staged tile visible
    // K strip frags (A-operand): keys 32w+16a+l15
    short8 kf[2][2];
#pragma unroll
    for (int a = 0; a < 2; a++)
#pragma unroll
      for (int h = 0; h < 2; h++)
        kf[a][h] = *(const short8*)(
            &sK[(32 * wave + 16 * a + l15) * 64 +
                ((((h << 2) | quad) ^ (l15 & 7)) << 3)]);
    // QK^T strip + exp2 + P write (wave-private sP)
#pragma unroll
    for (int a = 0; a < 2; a++)
#pragma unroll
      for (int g = 0; g < 4; g++) {
        f32x4 st = {0.f, 0.f, 0.f, 0.f};
        st = __builtin_amdgcn_mfma_f32_16x16x32_bf16(kf[a][0], qf[g][0], st, 0, 0, 0);
        st = __builtin_amdgcn_mfma_f32_16x16x32_bf16(kf[a][1], qf[g][1], st, 0, 0, 0);
        float p0 = exp2f(st[0]), p1 = exp2f(st[1]);
        float p2 = exp2f(st[2]), p3 = exp2f(st[3]);
        lsum[g] += (p0 + p1) + (p2 + p3);
        union { __hip_bfloat162 b; unsigned u; } a0, a1;
        a0.b = __float22bfloat162_rn(make_float2(p0, p1));
        a1.b = __float22bfloat162_rn(make_float2(p2, p3));
        uint2 w; w.x = a0.u; w.y = a1.u;
        *(uint2*)(pPw + (16 * g + l15) * 20 + 8 * a + 2 * quad) = w;
      }
    // P B-frags + V^T A-frags, then PV
    union { unsigned u[4]; short8 s; } pf[4];
#pragma unroll
    for (int g = 0; g < 4; g++)
      *(uint4*)pf[g].u = *(const uint4*)(pPw + (16 * g + l15) * 20 + 4 * quad);
    short8 vf[4];
#pragma unroll
    for (int nt = 0; nt < 4; nt++)
      vf[nt] = *(const short8*)(
          &sV[(16 * nt + l15) * 128 + (((4 * wave + quad) ^ l15) << 3)]);
#pragma unroll
    for (int nt = 0; nt < 4; nt++)
#pragma unroll
      for (int g = 0; g < 4; g++)
        o[nt][g] = __builtin_amdgcn_mfma_f32_16x16x32_bf16(
            vf[nt], pf[g].s, o[nt][g], 0, 0, 0);
  }

  // ---- cross-wave reduction of O^T and lsum ----
#pragma unroll
  for (int g = 0; g < 4; g++) {
    lsum[g] += __shfl_xor(lsum[g], 16, 64);
    lsum[g] += __shfl_xor(lsum[g], 32, 64);
  }
  float* redO = (float*)smem;                 // 2 x 64 x 68 floats (stride 68)
  float* redL = (float*)smem + 8704;          // 2 x 64
  __syncthreads();
  if (wave >= 2) {
    float* d = redO + (wave - 2) * 4352 + lane * 68;
#pragma unroll
    for (int nt = 0; nt < 4; nt++)
#pragma unroll
      for (int g = 0; g < 4; g++)
        *(f32x4*)(d + nt * 16 + g * 4) = o[nt][g];
    if (quad == 0)
#pragma unroll
      for (int g = 0; g < 4; g++) redL[(wave - 2) * 64 + g * 16 + l15] = lsum[g];
  }
  __syncthreads();
  if (wave < 2) {
    float* s = redO + wave * 4352 + lane * 68;
#pragma unroll
    for (int nt = 0; nt < 4; nt++)
#pragma unroll
      for (int g = 0; g < 4; g++) {
        f32x4 v = *(const f32x4*)(s + nt * 16 + g * 4);
#pragma unroll
        for (int r = 0; r < 4; r++) o[nt][g][r] += v[r];
      }
#pragma unroll
    for (int g = 0; g < 4; g++) lsum[g] += redL[wave * 64 + g * 16 + l15];
  }
  __syncthreads();
  if (wave == 1) {
    float* d = redO + lane * 68;
#pragma unroll
    for (int nt = 0; nt < 4; nt++)
#pragma unroll
      for (int g = 0; g < 4; g++)
        *(f32x4*)(d + nt * 16 + g * 4) = o[nt][g];
    if (quad == 0)
#pragma unroll
      for (int g = 0; g < 4; g++) redL[g * 16 + l15] = lsum[g];
  }
  __syncthreads();
  if (wave == 0) {
    float* s = redO + lane * 68;
    int b = bh >> 3, h = bh & 7;
#pragma unroll
    for (int g = 0; g < 4; g++) {
      float inv = 1.0f / (lsum[g] + redL[g * 16 + l15]);
      size_t rowbase = ((size_t)b * 2048 + qrow0 + 16 * g + l15) * 512 +
                       h * 64 + 4 * quad;
#pragma unroll
      for (int nt = 0; nt < 4; nt++) {
        f32x4 v = *(const f32x4*)(s + nt * 16 + g * 4);
        union { short sh[4]; uint2 u; } pk;
#pragma unroll
        for (int r = 0; r < 4; r++) pk.sh[r] = f2bf((o[nt][g][r] + v[r]) * inv);
        *(uint2*)(Ob + rowbase + 16 * nt) = pk.u;
      }
    }
  }
}

// ---------- launch ----------
extern "C" void kernel_launch(void* const* d_in, const int* in_sizes, int n_in,
                              void* d_out, int out_size, void* d_ws, size_t ws_size,
                              hipStream_t stream) {
  const float* x   = (const float*)d_in[0];
  const float* ctx = (const float*)d_in[1];
  const float* wq  = (const float*)d_in[2];
  const float* bq  = (const float*)d_in[3];
  const float* wk  = (const float*)d_in[4];
  const float* bk  = (const float*)d_in[5];
  const float* wv  = (const float*)d_in[6];
  const float* bv  = (const float*)d_in[7];
  const float* wo  = (const float*)d_in[8];
  const float* bo  = (const float*)d_in[9];
  float* out = (float*)d_out;
  char* ws = (char*)d_ws;

  short* xb  = (short*)(ws);                          // 16 MB [8192,1024]
  short* cb  = (short*)(ws + (16ull << 20));          // 16 MB [8192,1024]
  short* wqt = (short*)(ws + (32ull << 20));          //  1 MB [512,1024]
  short* wkt = (short*)(ws + (33ull << 20));          //  1 MB
  short* wvt = (short*)(ws + (34ull << 20));          //  1 MB
  short* wot = (short*)(ws + (35ull << 20));          //  1 MB [1024,512]
  short* Qb  = (short*)(ws + (36ull << 20));          //  8 MB [32,2048,64]
  short* Kb  = (short*)(ws + (44ull << 20));          //  8 MB [32,2048,64]
  short* Vt  = (short*)(ws + (52ull << 20));          //  8 MB [32,64,2048]
  short* Ob  = (short*)(ws + (60ull << 20));          //  8 MB [8192,512]
  short* Vb  = Ob;   // V [b,h,n,dh] staging; dead before attn writes Ob

  cast_bf16_kernel<<<8192, 256, 0, stream>>>(x, xb, 1 << 23);
  cast_bf16_kernel<<<8192, 256, 0, stream>>>(ctx, cb, 1 << 23);
  transpose_cast_kernel<<<128, 256, 0, stream>>>(wq, wqt, 1024, 512);
  transpose_cast_kernel<<<128, 256, 0, stream>>>(wk, wkt, 1024, 512);
  transpose_cast_kernel<<<128, 256, 0, stream>>>(wv, wvt, 1024, 512);
  transpose_cast_kernel<<<128, 256, 0, stream>>>(wo, wot, 512, 1024);
  gemm_qkv<<<dim3(64, 4, 3), 256, 0, stream>>>(xb, cb, wqt, wkt, wvt,
                                               bq, bk, bv, Qb, Kb, Vb);
  vtrans_kernel<<<1024, 256, 0, stream>>>(Vb, Vt);
  attn_kernel<<<1024, 256, 0, stream>>>(Qb, Kb, Vt, Ob);
  gemm_out<<<dim3(64, 8), 256, 0, stream>>>(Ob, wot, bo, out);
}